// Round 2
// baseline (207.701 us; speedup 1.0000x reference)
//
#include <hip/hip_runtime.h>
#include <stdint.h>

#define N_T   3072
#define D_T   128
#define K_T   1536
#define FS_T  192
#define RES_T 1345
#define TOT_T (RES_T * FS_T)   // 258240
#define TINYF 1.17549435e-38f

// ---------------- deterministic LDS reduction helpers ----------------

__device__ __forceinline__ double redSum128(double v, double* sh, int t) {
  sh[t] = v; __syncthreads();
  if (t < 64) sh[t] += sh[t + 64];
  __syncthreads();
  if (t < 32) sh[t] += sh[t + 32];
  __syncthreads();
  if (t < 16) sh[t] += sh[t + 16];
  __syncthreads();
  if (t < 8)  sh[t] += sh[t + 8];
  __syncthreads();
  if (t < 4)  sh[t] += sh[t + 4];
  __syncthreads();
  if (t < 2)  sh[t] += sh[t + 2];
  __syncthreads();
  if (t < 1)  sh[t] += sh[t + 1];
  __syncthreads();
  double s = sh[0];
  __syncthreads();
  return s;
}

__device__ __forceinline__ double redSum192(double v, double* sh, int t) {
  sh[t] = v; __syncthreads();
  if (t < 64) sh[t] += sh[t + 128];   // fold 128..191 into 0..63
  __syncthreads();
  if (t < 64) sh[t] += sh[t + 64];
  __syncthreads();
  if (t < 32) sh[t] += sh[t + 32];
  __syncthreads();
  if (t < 16) sh[t] += sh[t + 16];
  __syncthreads();
  if (t < 8)  sh[t] += sh[t + 8];
  __syncthreads();
  if (t < 4)  sh[t] += sh[t + 4];
  __syncthreads();
  if (t < 2)  sh[t] += sh[t + 2];
  __syncthreads();
  if (t < 1)  sh[t] += sh[t + 1];
  __syncthreads();
  double s = sh[0];
  __syncthreads();
  return s;
}

__device__ __forceinline__ double redMax192(double v, double* sh, int t) {
  sh[t] = v; __syncthreads();
  if (t < 64) sh[t] = fmax(sh[t], sh[t + 128]);
  __syncthreads();
  if (t < 64) sh[t] = fmax(sh[t], sh[t + 64]);
  __syncthreads();
  if (t < 32) sh[t] = fmax(sh[t], sh[t + 32]);
  __syncthreads();
  if (t < 16) sh[t] = fmax(sh[t], sh[t + 16]);
  __syncthreads();
  if (t < 8)  sh[t] = fmax(sh[t], sh[t + 8]);
  __syncthreads();
  if (t < 4)  sh[t] = fmax(sh[t], sh[t + 4]);
  __syncthreads();
  if (t < 2)  sh[t] = fmax(sh[t], sh[t + 2]);
  __syncthreads();
  if (t < 1)  sh[t] = fmax(sh[t], sh[t + 1]);
  __syncthreads();
  double s = sh[0];
  __syncthreads();
  return s;
}

// ---------------- threefry-2x32 (exact JAX bits) ----------------

__device__ __forceinline__ uint32_t rotl32(uint32_t x, uint32_t r) {
  return (x << r) | (x >> (32u - r));
}

__device__ __forceinline__ void threefry2x32(uint32_t k0, uint32_t k1,
                                             uint32_t x0, uint32_t x1,
                                             uint32_t& o0, uint32_t& o1) {
  uint32_t ks0 = k0, ks1 = k1, ks2 = k0 ^ k1 ^ 0x1BD11BDAu;
  x0 += ks0; x1 += ks1;
  // block 0 (rot A), then += ks1, ks2+1
  x0 += x1; x1 = rotl32(x1, 13); x1 ^= x0;
  x0 += x1; x1 = rotl32(x1, 15); x1 ^= x0;
  x0 += x1; x1 = rotl32(x1, 26); x1 ^= x0;
  x0 += x1; x1 = rotl32(x1, 6);  x1 ^= x0;
  x0 += ks1; x1 += ks2 + 1u;
  // block 1 (rot B), then += ks2, ks0+2
  x0 += x1; x1 = rotl32(x1, 17); x1 ^= x0;
  x0 += x1; x1 = rotl32(x1, 29); x1 ^= x0;
  x0 += x1; x1 = rotl32(x1, 16); x1 ^= x0;
  x0 += x1; x1 = rotl32(x1, 24); x1 ^= x0;
  x0 += ks2; x1 += ks0 + 2u;
  // block 2 (rot A), then += ks0, ks1+3
  x0 += x1; x1 = rotl32(x1, 13); x1 ^= x0;
  x0 += x1; x1 = rotl32(x1, 15); x1 ^= x0;
  x0 += x1; x1 = rotl32(x1, 26); x1 ^= x0;
  x0 += x1; x1 = rotl32(x1, 6);  x1 ^= x0;
  x0 += ks0; x1 += ks1 + 3u;
  // block 3 (rot B), then += ks1, ks2+4
  x0 += x1; x1 = rotl32(x1, 17); x1 ^= x0;
  x0 += x1; x1 = rotl32(x1, 29); x1 ^= x0;
  x0 += x1; x1 = rotl32(x1, 16); x1 ^= x0;
  x0 += x1; x1 = rotl32(x1, 24); x1 ^= x0;
  x0 += ks1; x1 += ks2 + 4u;
  // block 4 (rot A), then += ks2, ks0+5
  x0 += x1; x1 = rotl32(x1, 13); x1 ^= x0;
  x0 += x1; x1 = rotl32(x1, 15); x1 ^= x0;
  x0 += x1; x1 = rotl32(x1, 26); x1 ^= x0;
  x0 += x1; x1 = rotl32(x1, 6);  x1 ^= x0;
  x0 += ks2; x1 += ks0 + 5u;
  o0 = x0; o1 = x1;
}

// gumbel noise for flat index i, JAX partitionable-threefry layout
// (default since jax 0.4.36/0.5.x): counter = uint64 iota, x0 = hi32 = 0,
// x1 = lo32 = i, 32-bit bits = o0 ^ o1.
__device__ __forceinline__ float jax_gumbel(uint32_t i) {
  uint32_t o0, o1;
  threefry2x32(0u, 777u, 0u, i, o0, o1);
  uint32_t bits = o0 ^ o1;
  uint32_t fb = (bits >> 9) | 0x3F800000u;
  float u = __uint_as_float(fb) - 1.0f;    // [0,1)
  float uu = fmaxf(TINYF, u + TINYF);      // == max(tiny, floats*(1-tiny)+tiny) in f32
  return -logf(-logf(uu));
}

// ---------------- K1: scores[i] = dot(x[i], score_w)  (f64, order-exact) ----------------
__global__ void k1_scores(const float* __restrict__ x, const float* __restrict__ sw,
                          double* __restrict__ scores) {
  __shared__ double sh[128];
  int i = blockIdx.x, t = threadIdx.x;
  double p = (double)x[i * D_T + t] * (double)sw[t];
  double s = redSum128(p, sh, t);
  if (t == 0) scores[i] = s;
}

// ---------------- K2: full-order rank -> perm (top-k desc, index-asc ties) ----------------
__global__ void k2_rank(const double* __restrict__ scores, int* __restrict__ perm) {
  __shared__ double sh[N_T];
  int t = threadIdx.x;
  for (int j = t; j < N_T; j += 256) sh[j] = scores[j];
  __syncthreads();
  int i = blockIdx.x * 256 + t;
  double si = sh[i];
  int rank = 0;
  for (int j = 0; j < N_T; ++j) {
    double sj = sh[j];
    rank += ((sj > si) || (sj == si && j < i)) ? 1 : 0;
  }
  if (rank < K_T) perm[rank] = i;
}

// ---------------- K3: per-selected-row attention dots a,b ----------------
__global__ void k3_ab(const float* __restrict__ x, const int* __restrict__ perm,
                      const float* __restrict__ att, double* __restrict__ a,
                      double* __restrict__ b) {
  __shared__ double sh[128];
  int r = blockIdx.x, t = threadIdx.x;
  int p = perm[r];
  double xv = (double)x[p * D_T + t];
  double sa = redSum128(xv * (double)att[t], sh, t);
  double sb = redSum128(xv * (double)att[D_T + t], sh, t);
  if (t == 0) { a[r] = sa; b[r] = sb; }
}

// ---------------- K4: per-row sm softmax + gk + sort; gk_sort -> d_out, sm_sort -> ws ----------------
__global__ void k4_row(const float* __restrict__ x, const int* __restrict__ perm,
                       const double* __restrict__ a, const double* __restrict__ b,
                       float* __restrict__ gk_sort, float* __restrict__ sm_sort) {
  __shared__ float  xr[D_T];
  __shared__ double sh[FS_T];
  __shared__ double gkS[FS_T];
  int r = blockIdx.x, f = threadIdx.x;
  int pr = perm[r];
  if (f < D_T) xr[f] = x[pr * D_T + f];
  __syncthreads();

  // softmax of sm_raw over the row
  double smr = a[r] + b[r + f];
  double mx = redMax192(smr, sh, f);
  double e = exp(smr - mx);
  double ssum = redSum192(e, sh, f);
  double sm = e / ssum;

  // squared distance ||xk[r] - xk[r+f]||^2 in f64
  int pd = perm[r + f];
  const float4* rowd = (const float4*)(x + (size_t)pd * D_T);
  const float4* rowr = (const float4*)xr;
  double sq = 0.0;
#pragma unroll 8
  for (int tt = 0; tt < D_T / 4; ++tt) {
    float4 u = rowr[tt];
    float4 v = rowd[tt];
    double d0 = (double)u.x - (double)v.x;
    double d1 = (double)u.y - (double)v.y;
    double d2 = (double)u.z - (double)v.z;
    double d3 = (double)u.w - (double)v.w;
    sq += d0 * d0 + d1 * d1 + d2 * d2 + d3 * d3;
  }
  double dist = sqrt(fmax(sq, 1e-24));
  double gk = exp(-dist * 0.5) - 1e-5;   // 2*SIGMA^2 = 2

  // stable descending rank within the row
  gkS[f] = gk;
  __syncthreads();
  int rank = 0;
  for (int j = 0; j < FS_T; ++j) {
    double gj = gkS[j];
    rank += ((gj > gk) || (gj == gk && j < f)) ? 1 : 0;
  }
  gk_sort[r * FS_T + rank] = (float)gk;
  sm_sort[r * FS_T + rank] = (float)sm;
}

// ---------------- K5: logits_col[f] = sum_r sm_sort[r][f] (deterministic) ----------------
__global__ void k5_colsum(const float* __restrict__ sm_sort, double* __restrict__ logits) {
  int f = threadIdx.x;   // 192 threads, 1 block
  double s = 0.0;
  for (int r = 0; r < RES_T; ++r) s += (double)sm_sort[r * FS_T + f];
  logits[f] = s;
}

// ---------------- K6: gumbel softmax + multiply (in-place on d_out) ----------------
__global__ void k6_out(const double* __restrict__ logits,
                       const int* __restrict__ epoch_p, float* __restrict__ out) {
  __shared__ double sh[FS_T];
  int r = blockIdx.x, f = threadIdx.x;
  int i = r * FS_T + f;
  float gkv = out[i];                     // gk_sort staged here by k4
  float g = jax_gumbel((uint32_t)i);
  // defensive epoch read: accept int or float bit patterns
  int ei = epoch_p[0];
  double epoch;
  if (ei >= 0 && ei <= 100000) epoch = (double)ei;
  else {
    float ef = __int_as_float(ei);
    epoch = (ef >= 0.0f && ef <= 100000.0f) ? (double)ef : 50.0;
  }
  double tau0 = 10.0 * pow(0.01, epoch / 100.0);
  double z;
  if (f == 0) z = -INFINITY;
  else        z = ((double)g + logits[f]) / tau0;
  double mx = redMax192(z, sh, f);
  double e = (f == 0) ? 0.0 : exp(z - mx);
  double ssum = redSum192(e, sh, f);
  out[i] = (float)((double)gkv * (e / ssum));
}

// ---------------- launcher ----------------
extern "C" void kernel_launch(void* const* d_in, const int* in_sizes, int n_in,
                              void* d_out, int out_size, void* d_ws, size_t ws_size,
                              hipStream_t stream) {
  const float* x   = (const float*)d_in[0];
  // d_in[1] = edge_index (unused by the reference)
  const float* sw  = (const float*)d_in[2];
  // d_in[3] = score_b (order-preserving constant shift; unused)
  const float* att = (const float*)d_in[4];
  const int* epoch = (const int*)d_in[5];
  float* out = (float*)d_out;

  char* ws = (char*)d_ws;
  double* scores = (double*)ws;                 // 3072 * 8
  double* a      = scores + N_T;                // 1536 * 8
  double* b      = a + K_T;                     // 1536 * 8
  double* logits = b + K_T;                     // 192 * 8
  int*    perm   = (int*)(logits + FS_T);       // 1536 * 4
  float*  sm_sort = (float*)(perm + K_T);       // 258240 * 4  (~1.09 MB total)

  k1_scores<<<N_T, 128, 0, stream>>>(x, sw, scores);
  k2_rank<<<N_T / 256, 256, 0, stream>>>(scores, perm);
  k3_ab<<<K_T, 128, 0, stream>>>(x, perm, att, a, b);
  k4_row<<<RES_T, FS_T, 0, stream>>>(x, perm, a, b, out, sm_sort);
  k5_colsum<<<1, FS_T, 0, stream>>>(sm_sort, logits);
  k6_out<<<RES_T, FS_T, 0, stream>>>(logits, epoch, out);
}

// Round 3
// 57.208 us; speedup vs baseline: 3.6306x; 3.6306x over previous
//
#include <hip/hip_runtime.h>
#include <stdint.h>

#define N_T   3072
#define D_T   128
#define K_T   1536
#define FS_T  192
#define RES_T 1345
#define TOT_T (RES_T * FS_T)   // 258240
#define TINYF 1.17549435e-38f

// ---------------- deterministic LDS reduction helpers ----------------

__device__ __forceinline__ double redSum128(double v, double* sh, int t) {
  sh[t] = v; __syncthreads();
  if (t < 64) sh[t] += sh[t + 64];
  __syncthreads();
  if (t < 32) sh[t] += sh[t + 32];
  __syncthreads();
  if (t < 16) sh[t] += sh[t + 16];
  __syncthreads();
  if (t < 8)  sh[t] += sh[t + 8];
  __syncthreads();
  if (t < 4)  sh[t] += sh[t + 4];
  __syncthreads();
  if (t < 2)  sh[t] += sh[t + 2];
  __syncthreads();
  if (t < 1)  sh[t] += sh[t + 1];
  __syncthreads();
  double s = sh[0];
  __syncthreads();
  return s;
}

__device__ __forceinline__ double redSum192(double v, double* sh, int t) {
  sh[t] = v; __syncthreads();
  if (t < 64) sh[t] += sh[t + 128];   // fold 128..191 into 0..63
  __syncthreads();
  if (t < 64) sh[t] += sh[t + 64];
  __syncthreads();
  if (t < 32) sh[t] += sh[t + 32];
  __syncthreads();
  if (t < 16) sh[t] += sh[t + 16];
  __syncthreads();
  if (t < 8)  sh[t] += sh[t + 8];
  __syncthreads();
  if (t < 4)  sh[t] += sh[t + 4];
  __syncthreads();
  if (t < 2)  sh[t] += sh[t + 2];
  __syncthreads();
  if (t < 1)  sh[t] += sh[t + 1];
  __syncthreads();
  double s = sh[0];
  __syncthreads();
  return s;
}

__device__ __forceinline__ double redMax192(double v, double* sh, int t) {
  sh[t] = v; __syncthreads();
  if (t < 64) sh[t] = fmax(sh[t], sh[t + 128]);
  __syncthreads();
  if (t < 64) sh[t] = fmax(sh[t], sh[t + 64]);
  __syncthreads();
  if (t < 32) sh[t] = fmax(sh[t], sh[t + 32]);
  __syncthreads();
  if (t < 16) sh[t] = fmax(sh[t], sh[t + 16]);
  __syncthreads();
  if (t < 8)  sh[t] = fmax(sh[t], sh[t + 8]);
  __syncthreads();
  if (t < 4)  sh[t] = fmax(sh[t], sh[t + 4]);
  __syncthreads();
  if (t < 2)  sh[t] = fmax(sh[t], sh[t + 2]);
  __syncthreads();
  if (t < 1)  sh[t] = fmax(sh[t], sh[t + 1]);
  __syncthreads();
  double s = sh[0];
  __syncthreads();
  return s;
}

__device__ __forceinline__ int redSumInt256(int v, int* sh, int t) {
  sh[t] = v; __syncthreads();
  if (t < 128) sh[t] += sh[t + 128];
  __syncthreads();
  if (t < 64) sh[t] += sh[t + 64];
  __syncthreads();
  if (t < 32) sh[t] += sh[t + 32];
  __syncthreads();
  if (t < 16) sh[t] += sh[t + 16];
  __syncthreads();
  if (t < 8)  sh[t] += sh[t + 8];
  __syncthreads();
  if (t < 4)  sh[t] += sh[t + 4];
  __syncthreads();
  if (t < 2)  sh[t] += sh[t + 2];
  __syncthreads();
  if (t < 1)  sh[t] += sh[t + 1];
  __syncthreads();
  int s = sh[0];
  __syncthreads();
  return s;
}

__device__ __forceinline__ double redSum256d(double v, double* sh, int t) {
  sh[t] = v; __syncthreads();
  if (t < 128) sh[t] += sh[t + 128];
  __syncthreads();
  if (t < 64) sh[t] += sh[t + 64];
  __syncthreads();
  if (t < 32) sh[t] += sh[t + 32];
  __syncthreads();
  if (t < 16) sh[t] += sh[t + 16];
  __syncthreads();
  if (t < 8)  sh[t] += sh[t + 8];
  __syncthreads();
  if (t < 4)  sh[t] += sh[t + 4];
  __syncthreads();
  if (t < 2)  sh[t] += sh[t + 2];
  __syncthreads();
  if (t < 1)  sh[t] += sh[t + 1];
  __syncthreads();
  double s = sh[0];
  __syncthreads();
  return s;
}

// ---------------- threefry-2x32 (exact JAX bits) ----------------

__device__ __forceinline__ uint32_t rotl32(uint32_t x, uint32_t r) {
  return (x << r) | (x >> (32u - r));
}

__device__ __forceinline__ void threefry2x32(uint32_t k0, uint32_t k1,
                                             uint32_t x0, uint32_t x1,
                                             uint32_t& o0, uint32_t& o1) {
  uint32_t ks0 = k0, ks1 = k1, ks2 = k0 ^ k1 ^ 0x1BD11BDAu;
  x0 += ks0; x1 += ks1;
  x0 += x1; x1 = rotl32(x1, 13); x1 ^= x0;
  x0 += x1; x1 = rotl32(x1, 15); x1 ^= x0;
  x0 += x1; x1 = rotl32(x1, 26); x1 ^= x0;
  x0 += x1; x1 = rotl32(x1, 6);  x1 ^= x0;
  x0 += ks1; x1 += ks2 + 1u;
  x0 += x1; x1 = rotl32(x1, 17); x1 ^= x0;
  x0 += x1; x1 = rotl32(x1, 29); x1 ^= x0;
  x0 += x1; x1 = rotl32(x1, 16); x1 ^= x0;
  x0 += x1; x1 = rotl32(x1, 24); x1 ^= x0;
  x0 += ks2; x1 += ks0 + 2u;
  x0 += x1; x1 = rotl32(x1, 13); x1 ^= x0;
  x0 += x1; x1 = rotl32(x1, 15); x1 ^= x0;
  x0 += x1; x1 = rotl32(x1, 26); x1 ^= x0;
  x0 += x1; x1 = rotl32(x1, 6);  x1 ^= x0;
  x0 += ks0; x1 += ks1 + 3u;
  x0 += x1; x1 = rotl32(x1, 17); x1 ^= x0;
  x0 += x1; x1 = rotl32(x1, 29); x1 ^= x0;
  x0 += x1; x1 = rotl32(x1, 16); x1 ^= x0;
  x0 += x1; x1 = rotl32(x1, 24); x1 ^= x0;
  x0 += ks1; x1 += ks2 + 4u;
  x0 += x1; x1 = rotl32(x1, 13); x1 ^= x0;
  x0 += x1; x1 = rotl32(x1, 15); x1 ^= x0;
  x0 += x1; x1 = rotl32(x1, 26); x1 ^= x0;
  x0 += x1; x1 = rotl32(x1, 6);  x1 ^= x0;
  x0 += ks2; x1 += ks0 + 5u;
  o0 = x0; o1 = x1;
}

// gumbel noise for flat index i, JAX partitionable-threefry layout:
// counter = uint64 iota, x0 = hi32 = 0, x1 = lo32 = i, bits = o0 ^ o1.
__device__ __forceinline__ float jax_gumbel(uint32_t i) {
  uint32_t o0, o1;
  threefry2x32(0u, 777u, 0u, i, o0, o1);
  uint32_t bits = o0 ^ o1;
  uint32_t fb = (bits >> 9) | 0x3F800000u;
  float u = __uint_as_float(fb) - 1.0f;    // [0,1)
  float uu = fmaxf(TINYF, u + TINYF);
  return -logf(-logf(uu));
}

// ---------------- K1: scores[i] = dot(x[i], score_w)  (f64, order-exact) ----------------
__global__ void k1_scores(const float* __restrict__ x, const float* __restrict__ sw,
                          double* __restrict__ scores) {
  __shared__ double sh[128];
  int i = blockIdx.x, t = threadIdx.x;
  double p = (double)x[i * D_T + t] * (double)sw[t];
  double s = redSum128(p, sh, t);
  if (t == 0) scores[i] = s;
}

// ---------------- K2: block-per-element rank -> perm ----------------
// rank(i) = #{j : s[j] > s[i]  or  (s[j]==s[i] and j<i)}; if rank<K, perm[rank]=i.
__global__ void k2_rank(const double* __restrict__ scores, int* __restrict__ perm) {
  __shared__ int shi[256];
  int i = blockIdx.x, t = threadIdx.x;
  double si = scores[i];
  int cnt = 0;
#pragma unroll 4
  for (int j = t; j < N_T; j += 256) {
    double sj = scores[j];
    cnt += ((sj > si) || (sj == si && j < i)) ? 1 : 0;
  }
  int rank = redSumInt256(cnt, shi, t);
  if (t == 0 && rank < K_T) perm[rank] = i;
}

// ---------------- K3: per-selected-row attention dots a,b ----------------
__global__ void k3_ab(const float* __restrict__ x, const int* __restrict__ perm,
                      const float* __restrict__ att, double* __restrict__ a,
                      double* __restrict__ b) {
  __shared__ double sh[128];
  int r = blockIdx.x, t = threadIdx.x;
  int p = perm[r];
  double xv = (double)x[p * D_T + t];
  double sa = redSum128(xv * (double)att[t], sh, t);
  double sb = redSum128(xv * (double)att[D_T + t], sh, t);
  if (t == 0) { a[r] = sa; b[r] = sb; }
}

// ---------------- K4: per-row sm softmax + gk + sort; gk_sort -> d_out, sm_sort -> ws ----------------
__global__ void k4_row(const float* __restrict__ x, const int* __restrict__ perm,
                       const double* __restrict__ a, const double* __restrict__ b,
                       float* __restrict__ gk_sort, float* __restrict__ sm_sort) {
  __shared__ float  xr[D_T];
  __shared__ double sh[FS_T];
  __shared__ double gkS[FS_T];
  int r = blockIdx.x, f = threadIdx.x;
  int pr = perm[r];
  if (f < D_T) xr[f] = x[pr * D_T + f];
  __syncthreads();

  // softmax of sm_raw over the row
  double smr = a[r] + b[r + f];
  double mx = redMax192(smr, sh, f);
  double e = exp(smr - mx);
  double ssum = redSum192(e, sh, f);
  double sm = e / ssum;

  // squared distance ||xk[r] - xk[r+f]||^2 in f64
  int pd = perm[r + f];
  const float4* rowd = (const float4*)(x + (size_t)pd * D_T);
  const float4* rowr = (const float4*)xr;
  double sq = 0.0;
#pragma unroll 8
  for (int tt = 0; tt < D_T / 4; ++tt) {
    float4 u = rowr[tt];
    float4 v = rowd[tt];
    double d0 = (double)u.x - (double)v.x;
    double d1 = (double)u.y - (double)v.y;
    double d2 = (double)u.z - (double)v.z;
    double d3 = (double)u.w - (double)v.w;
    sq += d0 * d0 + d1 * d1 + d2 * d2 + d3 * d3;
  }
  double dist = sqrt(fmax(sq, 1e-24));
  double gk = exp(-dist * 0.5) - 1e-5;   // 2*SIGMA^2 = 2

  // stable descending rank within the row
  gkS[f] = gk;
  __syncthreads();
  int rank = 0;
#pragma unroll 8
  for (int j = 0; j < FS_T; ++j) {
    double gj = gkS[j];
    rank += ((gj > gk) || (gj == gk && j < f)) ? 1 : 0;
  }
  gk_sort[r * FS_T + rank] = (float)gk;
  sm_sort[r * FS_T + rank] = (float)sm;
}

// ---------------- K5: block-per-column logits[f] = sum_r sm_sort[r][f] ----------------
__global__ void k5_colsum(const float* __restrict__ sm_sort, double* __restrict__ logits) {
  __shared__ double sh[256];
  int f = blockIdx.x, t = threadIdx.x;
  double s = 0.0;
  for (int r = t; r < RES_T; r += 256) s += (double)sm_sort[r * FS_T + f];
  double tot = redSum256d(s, sh, t);
  if (t == 0) logits[f] = tot;
}

// ---------------- K6: gumbel softmax + multiply (in-place on d_out) ----------------
__global__ void k6_out(const double* __restrict__ logits,
                       const int* __restrict__ epoch_p, float* __restrict__ out) {
  __shared__ double sh[FS_T];
  int r = blockIdx.x, f = threadIdx.x;
  int i = r * FS_T + f;
  float gkv = out[i];                     // gk_sort staged here by k4
  float g = jax_gumbel((uint32_t)i);
  // defensive epoch read: accept int or float bit patterns
  int ei = epoch_p[0];
  double epoch;
  if (ei >= 0 && ei <= 100000) epoch = (double)ei;
  else {
    float ef = __int_as_float(ei);
    epoch = (ef >= 0.0f && ef <= 100000.0f) ? (double)ef : 50.0;
  }
  double tau0 = 10.0 * pow(0.01, epoch / 100.0);
  double z;
  if (f == 0) z = -INFINITY;
  else        z = ((double)g + logits[f]) / tau0;
  double mx = redMax192(z, sh, f);
  double e = (f == 0) ? 0.0 : exp(z - mx);
  double ssum = redSum192(e, sh, f);
  out[i] = (float)((double)gkv * (e / ssum));
}

// ---------------- launcher ----------------
extern "C" void kernel_launch(void* const* d_in, const int* in_sizes, int n_in,
                              void* d_out, int out_size, void* d_ws, size_t ws_size,
                              hipStream_t stream) {
  const float* x   = (const float*)d_in[0];
  // d_in[1] = edge_index (unused by the reference)
  const float* sw  = (const float*)d_in[2];
  // d_in[3] = score_b (order-preserving constant shift; unused)
  const float* att = (const float*)d_in[4];
  const int* epoch = (const int*)d_in[5];
  float* out = (float*)d_out;

  char* ws = (char*)d_ws;
  double* scores = (double*)ws;                 // 3072 * 8
  double* a      = scores + N_T;                // 1536 * 8
  double* b      = a + K_T;                     // 1536 * 8
  double* logits = b + K_T;                     // 192 * 8
  int*    perm   = (int*)(logits + FS_T);       // 1536 * 4
  float*  sm_sort = (float*)(perm + K_T);       // 258240 * 4  (~1.09 MB total)

  k1_scores<<<N_T, 128, 0, stream>>>(x, sw, scores);
  k2_rank<<<N_T, 256, 0, stream>>>(scores, perm);
  k3_ab<<<K_T, 128, 0, stream>>>(x, perm, att, a, b);
  k4_row<<<RES_T, FS_T, 0, stream>>>(x, perm, a, b, out, sm_sort);
  k5_colsum<<<FS_T, 256, 0, stream>>>(sm_sort, logits);
  k6_out<<<RES_T, FS_T, 0, stream>>>(logits, epoch, out);
}

// Round 4
// 55.517 us; speedup vs baseline: 3.7412x; 1.0305x over previous
//
#include <hip/hip_runtime.h>
#include <stdint.h>

#define N_T   3072
#define D_T   128
#define K_T   1536
#define FS_T  192
#define RES_T 1345
#define TOT_T (RES_T * FS_T)   // 258240
#define TINYF 1.17549435e-38f

// ---------------- wave-level reductions (64 lanes, fixed order, deterministic) ----------------

__device__ __forceinline__ double wsumd(double v) {
  v += __shfl_xor(v, 1);  v += __shfl_xor(v, 2);  v += __shfl_xor(v, 4);
  v += __shfl_xor(v, 8);  v += __shfl_xor(v, 16); v += __shfl_xor(v, 32);
  return v;
}
__device__ __forceinline__ double wmaxd(double v) {
  v = fmax(v, __shfl_xor(v, 1));  v = fmax(v, __shfl_xor(v, 2));
  v = fmax(v, __shfl_xor(v, 4));  v = fmax(v, __shfl_xor(v, 8));
  v = fmax(v, __shfl_xor(v, 16)); v = fmax(v, __shfl_xor(v, 32));
  return v;
}
__device__ __forceinline__ float wsumf(float v) {
  v += __shfl_xor(v, 1);  v += __shfl_xor(v, 2);  v += __shfl_xor(v, 4);
  v += __shfl_xor(v, 8);  v += __shfl_xor(v, 16); v += __shfl_xor(v, 32);
  return v;
}
__device__ __forceinline__ float wmaxf(float v) {
  v = fmaxf(v, __shfl_xor(v, 1));  v = fmaxf(v, __shfl_xor(v, 2));
  v = fmaxf(v, __shfl_xor(v, 4));  v = fmaxf(v, __shfl_xor(v, 8));
  v = fmaxf(v, __shfl_xor(v, 16)); v = fmaxf(v, __shfl_xor(v, 32));
  return v;
}
__device__ __forceinline__ int wsumi(int v) {
  v += __shfl_xor(v, 1);  v += __shfl_xor(v, 2);  v += __shfl_xor(v, 4);
  v += __shfl_xor(v, 8);  v += __shfl_xor(v, 16); v += __shfl_xor(v, 32);
  return v;
}

// ---------------- threefry-2x32 (exact JAX bits, partitionable layout) ----------------

__device__ __forceinline__ uint32_t rotl32(uint32_t x, uint32_t r) {
  return (x << r) | (x >> (32u - r));
}

__device__ __forceinline__ void threefry2x32(uint32_t k0, uint32_t k1,
                                             uint32_t x0, uint32_t x1,
                                             uint32_t& o0, uint32_t& o1) {
  uint32_t ks0 = k0, ks1 = k1, ks2 = k0 ^ k1 ^ 0x1BD11BDAu;
  x0 += ks0; x1 += ks1;
  x0 += x1; x1 = rotl32(x1, 13); x1 ^= x0;
  x0 += x1; x1 = rotl32(x1, 15); x1 ^= x0;
  x0 += x1; x1 = rotl32(x1, 26); x1 ^= x0;
  x0 += x1; x1 = rotl32(x1, 6);  x1 ^= x0;
  x0 += ks1; x1 += ks2 + 1u;
  x0 += x1; x1 = rotl32(x1, 17); x1 ^= x0;
  x0 += x1; x1 = rotl32(x1, 29); x1 ^= x0;
  x0 += x1; x1 = rotl32(x1, 16); x1 ^= x0;
  x0 += x1; x1 = rotl32(x1, 24); x1 ^= x0;
  x0 += ks2; x1 += ks0 + 2u;
  x0 += x1; x1 = rotl32(x1, 13); x1 ^= x0;
  x0 += x1; x1 = rotl32(x1, 15); x1 ^= x0;
  x0 += x1; x1 = rotl32(x1, 26); x1 ^= x0;
  x0 += x1; x1 = rotl32(x1, 6);  x1 ^= x0;
  x0 += ks0; x1 += ks1 + 3u;
  x0 += x1; x1 = rotl32(x1, 17); x1 ^= x0;
  x0 += x1; x1 = rotl32(x1, 29); x1 ^= x0;
  x0 += x1; x1 = rotl32(x1, 16); x1 ^= x0;
  x0 += x1; x1 = rotl32(x1, 24); x1 ^= x0;
  x0 += ks1; x1 += ks2 + 4u;
  x0 += x1; x1 = rotl32(x1, 13); x1 ^= x0;
  x0 += x1; x1 = rotl32(x1, 15); x1 ^= x0;
  x0 += x1; x1 = rotl32(x1, 26); x1 ^= x0;
  x0 += x1; x1 = rotl32(x1, 6);  x1 ^= x0;
  x0 += ks2; x1 += ks0 + 5u;
  o0 = x0; o1 = x1;
}

// gumbel for flat index i: counter = uint64 iota -> (hi=0, lo=i), bits = o0^o1
__device__ __forceinline__ float jax_gumbel(uint32_t i) {
  uint32_t o0, o1;
  threefry2x32(0u, 777u, 0u, i, o0, o1);
  uint32_t bits = o0 ^ o1;
  uint32_t fb = (bits >> 9) | 0x3F800000u;
  float u = __uint_as_float(fb) - 1.0f;    // [0,1)
  float uu = fmaxf(TINYF, u + TINYF);
  return -logf(-logf(uu));
}

// ---------------- K13: per-row score and b-dot (all N rows, f64) ----------------
// scores[i] = dot(x[i], sw);  ball[i] = dot(x[i], wb)   (wa is dead: softmax shift-invariance)
__global__ void k13_dots(const float* __restrict__ x, const float* __restrict__ sw,
                         const float* __restrict__ att,
                         double* __restrict__ scores, double* __restrict__ ball) {
  __shared__ double shA[2], shB[2];
  int i = blockIdx.x, t = threadIdx.x;       // 128 threads = 2 waves
  double xv = (double)x[i * D_T + t];
  double ps = wsumd(xv * (double)sw[t]);
  double pb = wsumd(xv * (double)att[D_T + t]);
  int w = t >> 6;
  if ((t & 63) == 0) { shA[w] = ps; shB[w] = pb; }
  __syncthreads();
  if (t == 0) { scores[i] = shA[0] + shA[1]; ball[i] = shB[0] + shB[1]; }
}

// ---------------- K2: block-per-element rank -> perm ----------------
__global__ void k2_rank(const double* __restrict__ scores, int* __restrict__ perm) {
  __shared__ int shi[4];
  int i = blockIdx.x, t = threadIdx.x;       // 256 threads
  double si = scores[i];
  int cnt = 0;
#pragma unroll
  for (int jj = 0; jj < 12; ++jj) {          // 12*256 = 3072 exactly
    int j = t + jj * 256;
    double sj = scores[j];
    cnt += ((sj > si) || (sj == si && j < i)) ? 1 : 0;
  }
  cnt = wsumi(cnt);
  int w = t >> 6;
  if ((t & 63) == 0) shi[w] = cnt;
  __syncthreads();
  if (t == 0) {
    int rank = shi[0] + shi[1] + shi[2] + shi[3];
    if (rank < K_T) perm[rank] = i;
  }
}

// ---------------- K4: per-row softmax + gk + stable rank; gk_sort->d_out, sm_sort->ws ----------------
__global__ void k4_row(const float* __restrict__ x, const int* __restrict__ perm,
                       const double* __restrict__ ball,
                       float* __restrict__ gk_sort, float* __restrict__ sm_sort) {
  __shared__ float  xr[D_T];
  __shared__ double gkS[FS_T];
  __shared__ double shm[3], shs[3];
  int r = blockIdx.x, f = threadIdx.x, w = f >> 6;   // 192 threads = 3 waves
  int pr = perm[r];
  int pd = perm[r + f];
  if (f < D_T) xr[f] = x[pr * D_T + f];

  // softmax over f of b[pd]  (the a_r shift is dropped — shift-invariant)
  double smr = ball[pd];
  double m = wmaxd(smr);
  if ((f & 63) == 0) shm[w] = m;
  __syncthreads();                                   // also publishes xr
  double mx = fmax(fmax(shm[0], shm[1]), shm[2]);
  double e = exp(smr - mx);
  double s = wsumd(e);
  if ((f & 63) == 0) shs[w] = s;
  __syncthreads();
  double sm = e / (shs[0] + shs[1] + shs[2]);

  // squared distance ||x[pr] - x[pd]||^2 in f64
  const float4* rowd = (const float4*)(x + (size_t)pd * D_T);
  const float4* rowr = (const float4*)xr;
  double sq = 0.0;
#pragma unroll
  for (int tt = 0; tt < D_T / 4; ++tt) {
    float4 u = rowr[tt];
    float4 v = rowd[tt];
    double d0 = (double)u.x - (double)v.x;
    double d1 = (double)u.y - (double)v.y;
    double d2 = (double)u.z - (double)v.z;
    double d3 = (double)u.w - (double)v.w;
    sq += d0 * d0 + d1 * d1 + d2 * d2 + d3 * d3;
  }
  double dist = sqrt(fmax(sq, 1e-24));
  double gk = exp(-dist * 0.5) - 1e-5;               // 2*SIGMA^2 = 2

  // stable descending rank within the row
  gkS[f] = gk;
  __syncthreads();
  int rank = 0;
#pragma unroll 8
  for (int j = 0; j < FS_T; ++j) {
    double gj = gkS[j];
    rank += ((gj > gk) || (gj == gk && j < f)) ? 1 : 0;
  }
  gk_sort[r * FS_T + rank] = (float)gk;
  sm_sort[r * FS_T + rank] = (float)sm;
}

// ---------------- K5: block-per-column logits[f] = sum_r sm_sort[r][f] ----------------
__global__ void k5_colsum(const float* __restrict__ sm_sort, double* __restrict__ logits) {
  __shared__ double shd[4];
  int f = blockIdx.x, t = threadIdx.x;       // 256 threads
  double s = 0.0;
  for (int r = t; r < RES_T; r += 256) s += (double)sm_sort[r * FS_T + f];
  s = wsumd(s);
  int w = t >> 6;
  if ((t & 63) == 0) shd[w] = s;
  __syncthreads();
  if (t == 0) logits[f] = shd[0] + shd[1] + shd[2] + shd[3];
}

// ---------------- K6: gumbel softmax + multiply (f32; in-place on d_out) ----------------
__global__ void k6_out(const double* __restrict__ logits,
                       const int* __restrict__ epoch_p, float* __restrict__ out) {
  __shared__ float shm[3], shs[3];
  int r = blockIdx.x, f = threadIdx.x, w = f >> 6;   // 192 threads = 3 waves
  int i = r * FS_T + f;
  float gkv = out[i];                                // gk_sort staged by k4
  float g = jax_gumbel((uint32_t)i);
  // defensive epoch read: accept int or float bit patterns
  int ei = epoch_p[0];
  double epoch;
  if (ei >= 0 && ei <= 100000) epoch = (double)ei;
  else {
    float ef = __int_as_float(ei);
    epoch = (ef >= 0.0f && ef <= 100000.0f) ? (double)ef : 50.0;
  }
  // invtau = 1/tau0 = 0.1 * exp(+ln(100)/100 * epoch)
  double invtau = 0.1 * exp(0.04605170185988091 * epoch);
  float z = (f == 0) ? -INFINITY : (float)(((double)g + logits[f]) * invtau);
  float m = wmaxf(z);
  if ((f & 63) == 0) shm[w] = m;
  __syncthreads();
  float mx = fmaxf(fmaxf(shm[0], shm[1]), shm[2]);
  float e = (f == 0) ? 0.0f : expf(z - mx);
  float s = wsumf(e);
  if ((f & 63) == 0) shs[w] = s;
  __syncthreads();
  float ssum = shs[0] + shs[1] + shs[2];
  out[i] = gkv * (e / ssum);
}

// ---------------- launcher ----------------
extern "C" void kernel_launch(void* const* d_in, const int* in_sizes, int n_in,
                              void* d_out, int out_size, void* d_ws, size_t ws_size,
                              hipStream_t stream) {
  const float* x   = (const float*)d_in[0];
  // d_in[1] = edge_index (unused by the reference)
  const float* sw  = (const float*)d_in[2];
  // d_in[3] = score_b (order-preserving constant shift; unused)
  const float* att = (const float*)d_in[4];
  const int* epoch = (const int*)d_in[5];
  float* out = (float*)d_out;

  char* ws = (char*)d_ws;
  double* scores = (double*)ws;                 // 3072 * 8
  double* ball   = scores + N_T;                // 3072 * 8
  double* logits = ball + N_T;                  // 192 * 8
  int*    perm   = (int*)(logits + FS_T);       // 1536 * 4
  float*  sm_sort = (float*)(perm + K_T);       // 258240 * 4  (~1.1 MB total)

  k13_dots<<<N_T, 128, 0, stream>>>(x, sw, att, scores, ball);
  k2_rank<<<N_T, 256, 0, stream>>>(scores, perm);
  k4_row<<<RES_T, FS_T, 0, stream>>>(x, perm, ball, out, sm_sort);
  k5_colsum<<<FS_T, 256, 0, stream>>>(sm_sort, logits);
  k6_out<<<RES_T, FS_T, 0, stream>>>(logits, epoch, out);
}